// Round 3
// baseline (690.823 us; speedup 1.0000x reference)
//
#include <hip/hip_runtime.h>

#define L  2048
#define D  64
#define NH 16
#define NB 2

using half8   = _Float16 __attribute__((ext_vector_type(8)));
using half4v  = _Float16 __attribute__((ext_vector_type(4)));
using float4v = float    __attribute__((ext_vector_type(4)));
using int4v   = int      __attribute__((ext_vector_type(4)));

// ---------------- precompute: qh = fp16(q/8), kh = fp16(k) ----------------
__global__ __launch_bounds__(256) void prep_qk(const float* __restrict__ q,
                                               const float* __restrict__ k,
                                               _Float16* __restrict__ qh,
                                               _Float16* __restrict__ kh) {
    int i = (blockIdx.x * 256 + threadIdx.x) * 8;
    float4v a0 = *(const float4v*)(q + i);
    float4v a1 = *(const float4v*)(q + i + 4);
    float4v b0 = *(const float4v*)(k + i);
    float4v b1 = *(const float4v*)(k + i + 4);
    half8 qo, ko;
#pragma unroll
    for (int j = 0; j < 4; ++j) {
        qo[j]     = (_Float16)(a0[j] * 0.125f);   // fold 1/TEMPERATURE
        qo[4 + j] = (_Float16)(a1[j] * 0.125f);
        ko[j]     = (_Float16)b0[j];
        ko[4 + j] = (_Float16)b1[j];
    }
    *(half8*)(qh + i) = qo;
    *(half8*)(kh + i) = ko;
}

// ---------------- precompute: vt[b,h,d,l] = fp16(v[b,h,l,d]) ----------------
__global__ __launch_bounds__(256) void prep_vt(const float* __restrict__ v,
                                               _Float16* __restrict__ vt) {
    __shared__ float tile[64][65];
    int bh = blockIdx.x >> 5;          // 0..31
    int l0 = (blockIdx.x & 31) * 64;
    const float* vb = v + (size_t)bh * L * D + (size_t)l0 * D;
    int row = threadIdx.x >> 2, c0 = (threadIdx.x & 3) * 16;
#pragma unroll
    for (int j = 0; j < 16; j += 4) {
        float4v t4 = *(const float4v*)(vb + row * D + c0 + j);
        tile[row][c0 + j + 0] = t4[0];
        tile[row][c0 + j + 1] = t4[1];
        tile[row][c0 + j + 2] = t4[2];
        tile[row][c0 + j + 3] = t4[3];
    }
    __syncthreads();
    int d = threadIdx.x >> 2, lq = (threadIdx.x & 3) * 16;
    _Float16* ob = vt + (size_t)bh * D * L + (size_t)d * L + l0 + lq;
    half8 o0, o1;
#pragma unroll
    for (int j = 0; j < 8; ++j) {
        o0[j] = (_Float16)tile[lq + j][d];
        o1[j] = (_Float16)tile[lq + 8 + j][d];
    }
    *(half8*)(ob)     = o0;
    *(half8*)(ob + 8) = o1;
}

// ---------------- kernel A: scores + softmax + attn write ----------------
// block = (b, h, qtile of 16 rows), 4 waves; wave w owns keys [512w,512w+512).
// Swapped QK (mfma(K,Q)): lane holds 4 consecutive keys of one q-row (cg).
// e kept UNNORMALIZED as packed fp16 (64 VGPRs). No PV, ~0 LDS -> 3 blocks/CU.
__global__ __launch_bounds__(256, 3) void attn_scores(const _Float16* __restrict__ qh,
                                                      const _Float16* __restrict__ kh,
                                                      const int* __restrict__ mask,
                                                      const float* __restrict__ bias,
                                                      float* __restrict__ out_attn) {
    __shared__ float lpart[4][16];

    int p  = blockIdx.x;                       // XCD-chunked swizzle: 4 heads/XCD
    int l  = (p & 7) * 512 + (p >> 3);
    int h1 = l & 3, qt = (l >> 2) & 127, h2 = (l >> 9) & 3, b = l >> 11;
    int h  = h2 * 4 + h1;
    int bh = b * NH + h;
    int q0 = qt * 16;

    int tid = threadIdx.x, w = tid >> 6, lane = tid & 63;
    int cg = lane & 15, grp = lane >> 4;

    const _Float16* qbase = qh + ((size_t)bh * L + q0) * D;
    const _Float16* kbase = kh + (size_t)bh * L * D;

    half8 aq0 = *(const half8*)(qbase + cg * D + grp * 8);
    half8 aq1 = *(const half8*)(qbase + cg * D + 32 + grp * 8);

    int k0w = w * 512;
    const size_t mrow = ((size_t)b * L + (q0 + cg)) * L;

    half4v puh[32];                            // unnormalized e, fp16 (64 VGPRs)
    float ls = 0.f;
#pragma unroll
    for (int f = 0; f < 32; ++f) {
        int n0 = k0w + f * 16;
        const _Float16* kb = kbase + (size_t)(n0 + cg) * D + grp * 8;
        half8 bk0 = *(const half8*)(kb);
        half8 bk1 = *(const half8*)(kb + 32);
        int4v   m4 = *(const int4v*)(mask + mrow + n0 + grp * 4);
        float4v b4 = *(const float4v*)(bias + mrow + n0 + grp * 4);
        float4v acc;
        acc[0] = m4[0] ? b4[0] : -1e9f;
        acc[1] = m4[1] ? b4[1] : -1e9f;
        acc[2] = m4[2] ? b4[2] : -1e9f;
        acc[3] = m4[3] ? b4[3] : -1e9f;
        acc = __builtin_amdgcn_mfma_f32_16x16x32_f16(bk0, aq0, acc, 0, 0, 0);
        acc = __builtin_amdgcn_mfma_f32_16x16x32_f16(bk1, aq1, acc, 0, 0, 0);
        float e0 = __expf(acc[0]), e1 = __expf(acc[1]);
        float e2 = __expf(acc[2]), e3 = __expf(acc[3]);
        ls += (e0 + e1) + (e2 + e3);
        half4v ph;
        ph[0] = (_Float16)e0; ph[1] = (_Float16)e1;
        ph[2] = (_Float16)e2; ph[3] = (_Float16)e3;
        puh[f] = ph;
    }

    ls += __shfl_xor(ls, 16);
    ls += __shfl_xor(ls, 32);
    if (grp == 0) lpart[w][cg] = ls;
    __syncthreads();
    float rl = 1.0f / (lpart[0][cg] + lpart[1][cg] + lpart[2][cg] + lpart[3][cg]);

    float* abase = out_attn + ((size_t)bh * L + (q0 + cg)) * L;
#pragma unroll
    for (int f = 0; f < 32; ++f) {
        int key = k0w + f * 16 + grp * 4;
        float4v pn;
        pn[0] = (float)puh[f][0] * rl;
        pn[1] = (float)puh[f][1] * rl;
        pn[2] = (float)puh[f][2] * rl;
        pn[3] = (float)puh[f][3] * rl;
        *(float4v*)(abase + key) = pn;
    }
}

// ---------------- kernel B: recompute QK + PV (standalone) ----------------
// 1024 blocks x 4 waves; wave = one 16-row q-tile x ALL 2048 keys. No barriers.
// Per 32-key step: QK-MFMA -> exp -> fp16 -> per-wave LDS bounce (C-frag ->
// A-frag layout) -> 4 PV MFMAs. Normalize by 1/l at the end (shfl broadcast).
__global__ __launch_bounds__(256, 4) void attn_pv(const _Float16* __restrict__ qh,
                                                  const _Float16* __restrict__ kh,
                                                  const _Float16* __restrict__ vt,
                                                  const int* __restrict__ mask,
                                                  const float* __restrict__ bias,
                                                  float* __restrict__ out_ho) {
    __shared__ _Float16 pt[4 * 2 * 16 * 40];   // per-wave 2-buf 16x32 tile, 80B rows

    int p  = blockIdx.x;                       // 1024 blocks, XCD swizzle
    int l  = (p & 7) * 128 + (p >> 3);
    int h1 = l & 3, qt4 = (l >> 2) & 31, h2 = (l >> 7) & 3, b = l >> 9;
    int h  = h2 * 4 + h1;
    int bh = b * NH + h;

    int tid = threadIdx.x, w = tid >> 6, lane = tid & 63;
    int cg = lane & 15, grp = lane >> 4;
    int q0 = qt4 * 64 + w * 16;

    const _Float16* qbase = qh + ((size_t)bh * L + q0) * D;
    const _Float16* kbase = kh + (size_t)bh * L * D;
    const _Float16* vbase = vt + (size_t)bh * D * L;

    half8 aq0 = *(const half8*)(qbase + cg * D + grp * 8);
    half8 aq1 = *(const half8*)(qbase + cg * D + 32 + grp * 8);

    const size_t mrow = ((size_t)b * L + (q0 + cg)) * L;
    _Float16* slice = pt + w * (2 * 640);

    float ls = 0.f;
    float4v oa0 = {0.f,0.f,0.f,0.f}, oa1 = {0.f,0.f,0.f,0.f};
    float4v oa2 = {0.f,0.f,0.f,0.f}, oa3 = {0.f,0.f,0.f,0.f};

#pragma unroll 4
    for (int s = 0; s < 64; ++s) {
        int n0 = s * 32;
        _Float16* tb = slice + (s & 1) * 640;
#pragma unroll
        for (int tl = 0; tl < 2; ++tl) {
            int nt = n0 + tl * 16;
            const _Float16* kb = kbase + (size_t)(nt + cg) * D + grp * 8;
            half8 bk0 = *(const half8*)(kb);
            half8 bk1 = *(const half8*)(kb + 32);
            int4v   m4 = *(const int4v*)(mask + mrow + nt + grp * 4);
            float4v b4 = *(const float4v*)(bias + mrow + nt + grp * 4);
            float4v acc;
            acc[0] = m4[0] ? b4[0] : -1e9f;
            acc[1] = m4[1] ? b4[1] : -1e9f;
            acc[2] = m4[2] ? b4[2] : -1e9f;
            acc[3] = m4[3] ? b4[3] : -1e9f;
            acc = __builtin_amdgcn_mfma_f32_16x16x32_f16(bk0, aq0, acc, 0, 0, 0);
            acc = __builtin_amdgcn_mfma_f32_16x16x32_f16(bk1, aq1, acc, 0, 0, 0);
            float e0 = __expf(acc[0]), e1 = __expf(acc[1]);
            float e2 = __expf(acc[2]), e3 = __expf(acc[3]);
            ls += (e0 + e1) + (e2 + e3);
            half4v ph;
            ph[0] = (_Float16)e0; ph[1] = (_Float16)e1;
            ph[2] = (_Float16)e2; ph[3] = (_Float16)e3;
            // P[q=cg][key = tl*16 + grp*4 .. +3] (unnormalized)
            *(half4v*)(tb + cg * 40 + tl * 16 + grp * 4) = ph;
        }
        // A-frag: P[q=cg][k-chunk grp*8..+7] over this 32-key step
        half8 pa = *(const half8*)(tb + cg * 40 + grp * 8);
        const _Float16* vb = vbase + n0 + grp * 8;
        half8 pv0 = *(const half8*)(vb + (size_t)(cg)      * L);
        half8 pv1 = *(const half8*)(vb + (size_t)(16 + cg) * L);
        half8 pv2 = *(const half8*)(vb + (size_t)(32 + cg) * L);
        half8 pv3 = *(const half8*)(vb + (size_t)(48 + cg) * L);
        oa0 = __builtin_amdgcn_mfma_f32_16x16x32_f16(pa, pv0, oa0, 0, 0, 0);
        oa1 = __builtin_amdgcn_mfma_f32_16x16x32_f16(pa, pv1, oa1, 0, 0, 0);
        oa2 = __builtin_amdgcn_mfma_f32_16x16x32_f16(pa, pv2, oa2, 0, 0, 0);
        oa3 = __builtin_amdgcn_mfma_f32_16x16x32_f16(pa, pv3, oa3, 0, 0, 0);
    }

    // l(q=cg) at every lane; broadcast l(q=grp*4+i) from lanes 0..15
    ls += __shfl_xor(ls, 16);
    ls += __shfl_xor(ls, 32);
    float r0 = 1.0f / __shfl(ls, grp * 4 + 0);
    float r1 = 1.0f / __shfl(ls, grp * 4 + 1);
    float r2 = 1.0f / __shfl(ls, grp * 4 + 2);
    float r3 = 1.0f / __shfl(ls, grp * 4 + 3);

    float* ob = out_ho + ((size_t)bh * L + q0) * D;
    ob[(size_t)(grp * 4 + 0) * D +  0 + cg] = oa0[0] * r0;
    ob[(size_t)(grp * 4 + 1) * D +  0 + cg] = oa0[1] * r1;
    ob[(size_t)(grp * 4 + 2) * D +  0 + cg] = oa0[2] * r2;
    ob[(size_t)(grp * 4 + 3) * D +  0 + cg] = oa0[3] * r3;
    ob[(size_t)(grp * 4 + 0) * D + 16 + cg] = oa1[0] * r0;
    ob[(size_t)(grp * 4 + 1) * D + 16 + cg] = oa1[1] * r1;
    ob[(size_t)(grp * 4 + 2) * D + 16 + cg] = oa1[2] * r2;
    ob[(size_t)(grp * 4 + 3) * D + 16 + cg] = oa1[3] * r3;
    ob[(size_t)(grp * 4 + 0) * D + 32 + cg] = oa2[0] * r0;
    ob[(size_t)(grp * 4 + 1) * D + 32 + cg] = oa2[1] * r1;
    ob[(size_t)(grp * 4 + 2) * D + 32 + cg] = oa2[2] * r2;
    ob[(size_t)(grp * 4 + 3) * D + 32 + cg] = oa2[3] * r3;
    ob[(size_t)(grp * 4 + 0) * D + 48 + cg] = oa3[0] * r0;
    ob[(size_t)(grp * 4 + 1) * D + 48 + cg] = oa3[1] * r1;
    ob[(size_t)(grp * 4 + 2) * D + 48 + cg] = oa3[2] * r2;
    ob[(size_t)(grp * 4 + 3) * D + 48 + cg] = oa3[3] * r3;
}

extern "C" void kernel_launch(void* const* d_in, const int* in_sizes, int n_in,
                              void* d_out, int out_size, void* d_ws, size_t ws_size,
                              hipStream_t stream) {
    const float* q    = (const float*)d_in[0];
    const float* k    = (const float*)d_in[1];
    const float* v    = (const float*)d_in[2];
    const int*   mask = (const int*)d_in[3];
    const float* bias = (const float*)d_in[4];

    float* ho   = (float*)d_out;
    float* attn = (float*)d_out + (size_t)NB * NH * L * D;

    char* ws = (char*)d_ws;
    _Float16* qh = (_Float16*)(ws);                       // 8 MB
    _Float16* kh = (_Float16*)(ws + ((size_t)8  << 20));  // 8 MB
    _Float16* vt = (_Float16*)(ws + ((size_t)16 << 20));  // 8 MB
    (void)in_sizes; (void)n_in; (void)out_size; (void)ws_size;

    prep_qk<<<2048, 256, 0, stream>>>(q, k, qh, kh);
    prep_vt<<<1024, 256, 0, stream>>>(v, vt);
    attn_scores<<<4096, 256, 0, stream>>>(qh, kh, mask, bias, attn);
    attn_pv<<<1024, 256, 0, stream>>>(qh, kh, vt, mask, bias, ho);
}

// Round 4
// 608.351 us; speedup vs baseline: 1.1356x; 1.1356x over previous
//
#include <hip/hip_runtime.h>

#define L  2048
#define D  64
#define NH 16
#define NB 2

using half8   = _Float16 __attribute__((ext_vector_type(8)));
using half4v  = _Float16 __attribute__((ext_vector_type(4)));
using float4v = float    __attribute__((ext_vector_type(4)));
using int4v   = int      __attribute__((ext_vector_type(4)));

// ---------------- precompute: qh = fp16(q/8), kh = fp16(k) ----------------
__global__ __launch_bounds__(256) void prep_qk(const float* __restrict__ q,
                                               const float* __restrict__ k,
                                               _Float16* __restrict__ qh,
                                               _Float16* __restrict__ kh) {
    int i = (blockIdx.x * 256 + threadIdx.x) * 8;
    float4v a0 = *(const float4v*)(q + i);
    float4v a1 = *(const float4v*)(q + i + 4);
    float4v b0 = *(const float4v*)(k + i);
    float4v b1 = *(const float4v*)(k + i + 4);
    half8 qo, ko;
#pragma unroll
    for (int j = 0; j < 4; ++j) {
        qo[j]     = (_Float16)(a0[j] * 0.125f);
        qo[4 + j] = (_Float16)(a1[j] * 0.125f);
        ko[j]     = (_Float16)b0[j];
        ko[4 + j] = (_Float16)b1[j];
    }
    *(half8*)(qh + i) = qo;
    *(half8*)(kh + i) = ko;
}

// ---------------- precompute: vt[b,h,d,l] = fp16(v[b,h,l,d]) ----------------
__global__ __launch_bounds__(256) void prep_vt(const float* __restrict__ v,
                                               _Float16* __restrict__ vt) {
    __shared__ float tile[64][65];
    int bh = blockIdx.x >> 5;
    int l0 = (blockIdx.x & 31) * 64;
    const float* vb = v + (size_t)bh * L * D + (size_t)l0 * D;
    int row = threadIdx.x >> 2, c0 = (threadIdx.x & 3) * 16;
#pragma unroll
    for (int j = 0; j < 16; j += 4) {
        float4v t4 = *(const float4v*)(vb + row * D + c0 + j);
        tile[row][c0 + j + 0] = t4[0];
        tile[row][c0 + j + 1] = t4[1];
        tile[row][c0 + j + 2] = t4[2];
        tile[row][c0 + j + 3] = t4[3];
    }
    __syncthreads();
    int d = threadIdx.x >> 2, lq = (threadIdx.x & 3) * 16;
    _Float16* ob = vt + (size_t)bh * D * L + (size_t)d * L + l0 + lq;
    half8 o0, o1;
#pragma unroll
    for (int j = 0; j < 8; ++j) {
        o0[j] = (_Float16)tile[lq + j][d];
        o1[j] = (_Float16)tile[lq + 8 + j][d];
    }
    *(half8*)(ob)     = o0;
    *(half8*)(ob + 8) = o1;
}

// ---------------- precompute: mbh = fp16(mask ? bias : -1000) ----------------
__global__ __launch_bounds__(256) void prep_mbh(const int* __restrict__ mask,
                                                const float* __restrict__ bias,
                                                _Float16* __restrict__ mbh) {
    int i = (blockIdx.x * 256 + threadIdx.x) * 8;
    half8 o;
#pragma unroll
    for (int j = 0; j < 8; j += 4) {
        int4v   m = *(const int4v*)(mask + i + j);
        float4v b = *(const float4v*)(bias + i + j);
        o[j + 0] = (_Float16)(m[0] ? b[0] : -1000.0f);
        o[j + 1] = (_Float16)(m[1] ? b[1] : -1000.0f);
        o[j + 2] = (_Float16)(m[2] ? b[2] : -1000.0f);
        o[j + 3] = (_Float16)(m[3] ? b[3] : -1000.0f);
    }
    *(half8*)(mbh + i) = o;
}

// ---------------- kernel A: scores + softmax + attn write ----------------
// Swapped QK (mfma(K,Q)); lane holds 4 consecutive keys of q-row cg.
// Depth-1 register prefetch of K-frags + mbh; e kept as fp16 e/16 (64 VGPRs).
__global__ __launch_bounds__(256, 4) void attn_scores(const _Float16* __restrict__ qh,
                                                      const _Float16* __restrict__ kh,
                                                      const _Float16* __restrict__ mbh,
                                                      float* __restrict__ out_attn) {
    __shared__ float lpart[4][16];

    int p  = blockIdx.x;                       // XCD-chunked: one (b,h2) per XCD
    int l  = (p & 7) * 512 + (p >> 3);
    int h1 = l & 3, qt = (l >> 2) & 127, h2 = (l >> 9) & 3, b = l >> 11;
    int h  = h2 * 4 + h1;
    int bh = b * NH + h;
    int q0 = qt * 16;

    int tid = threadIdx.x, w = tid >> 6, lane = tid & 63;
    int cg = lane & 15, grp = lane >> 4;

    const _Float16* qbase = qh + ((size_t)bh * L + q0) * D;
    const _Float16* kbase = kh + (size_t)bh * L * D;

    half8 aq0 = *(const half8*)(qbase + cg * D + grp * 8);
    half8 aq1 = *(const half8*)(qbase + cg * D + 32 + grp * 8);

    int k0w = w * 512;
    const _Float16* mrow = mbh + ((size_t)b * L + (q0 + cg)) * L;

    half4v puh[32];
    float ls = 0.f;

    half8 bkA0, bkA1, bkB0, bkB1;
    half4v mbA, mbB;
    {
        const _Float16* kb = kbase + (size_t)(k0w + cg) * D + grp * 8;
        bkA0 = *(const half8*)(kb);
        bkA1 = *(const half8*)(kb + 32);
        mbA  = *(const half4v*)(mrow + k0w + grp * 4);
    }
#pragma unroll
    for (int f = 0; f < 32; ++f) {
        if (f < 31) {                          // issue next step's loads early
            int n1 = k0w + (f + 1) * 16;
            const _Float16* kb = kbase + (size_t)(n1 + cg) * D + grp * 8;
            bkB0 = *(const half8*)(kb);
            bkB1 = *(const half8*)(kb + 32);
            mbB  = *(const half4v*)(mrow + n1 + grp * 4);
        }
        float4v acc;
        acc[0] = (float)mbA[0]; acc[1] = (float)mbA[1];
        acc[2] = (float)mbA[2]; acc[3] = (float)mbA[3];
        acc = __builtin_amdgcn_mfma_f32_16x16x32_f16(bkA0, aq0, acc, 0, 0, 0);
        acc = __builtin_amdgcn_mfma_f32_16x16x32_f16(bkA1, aq1, acc, 0, 0, 0);
        float e0 = __expf(acc[0]), e1 = __expf(acc[1]);
        float e2 = __expf(acc[2]), e3 = __expf(acc[3]);
        ls += (e0 + e1) + (e2 + e3);
        half4v ph;                             // store e/16: fp16 overflow headroom
        ph[0] = (_Float16)(e0 * 0.0625f); ph[1] = (_Float16)(e1 * 0.0625f);
        ph[2] = (_Float16)(e2 * 0.0625f); ph[3] = (_Float16)(e3 * 0.0625f);
        puh[f] = ph;
        bkA0 = bkB0; bkA1 = bkB1; mbA = mbB;
    }

    ls += __shfl_xor(ls, 16);
    ls += __shfl_xor(ls, 32);
    if (grp == 0) lpart[w][cg] = ls;
    __syncthreads();
    float rl = 16.0f / (lpart[0][cg] + lpart[1][cg] + lpart[2][cg] + lpart[3][cg]);

    float* abase = out_attn + ((size_t)bh * L + (q0 + cg)) * L;
#pragma unroll
    for (int f = 0; f < 32; ++f) {
        int key = k0w + f * 16 + grp * 4;
        float4v pn;
        pn[0] = (float)puh[f][0] * rl;
        pn[1] = (float)puh[f][1] * rl;
        pn[2] = (float)puh[f][2] * rl;
        pn[3] = (float)puh[f][3] * rl;
        *(float4v*)(abase + key) = pn;
    }
}

// ---------------- kernel B: recompute QK + PV, depth-1 prefetch ----------------
// 1024 blocks x 4 waves; wave = 16 q-rows x all 2048 keys, no barriers.
__global__ __launch_bounds__(256, 4) void attn_pv(const _Float16* __restrict__ qh,
                                                  const _Float16* __restrict__ kh,
                                                  const _Float16* __restrict__ vt,
                                                  const _Float16* __restrict__ mbh,
                                                  float* __restrict__ out_ho) {
    __shared__ _Float16 pt[4 * 2 * 640];       // per-wave 2-buf 16x32 P tile, 80B rows

    int p  = blockIdx.x;                       // one (b,h2) per XCD
    int l  = (p & 7) * 128 + (p >> 3);
    int h1 = l & 3, qt4 = (l >> 2) & 31, h2 = (l >> 7) & 3, b = l >> 9;
    int h  = h2 * 4 + h1;
    int bh = b * NH + h;

    int tid = threadIdx.x, w = tid >> 6, lane = tid & 63;
    int cg = lane & 15, grp = lane >> 4;
    int q0 = qt4 * 64 + w * 16;

    const _Float16* qbase = qh + ((size_t)bh * L + q0) * D;
    const _Float16* kbase = kh + (size_t)bh * L * D;
    const _Float16* vbase = vt + (size_t)bh * D * L;
    const _Float16* mrow  = mbh + ((size_t)b * L + (q0 + cg)) * L;

    half8 aq0 = *(const half8*)(qbase + cg * D + grp * 8);
    half8 aq1 = *(const half8*)(qbase + cg * D + 32 + grp * 8);

    _Float16* slice = pt + w * (2 * 640);

    float ls = 0.f;
    float4v oa0 = {0.f,0.f,0.f,0.f}, oa1 = {0.f,0.f,0.f,0.f};
    float4v oa2 = {0.f,0.f,0.f,0.f}, oa3 = {0.f,0.f,0.f,0.f};

    struct Pref {
        half8 bk00, bk01, bk10, bk11;          // K-frags, tiles 0/1
        half4v mb0, mb1;                       // mbh, tiles 0/1
        half8 v0, v1, v2, v3;                  // V-frags (4 d-blocks)
    };
    Pref A, B;

    auto load_step = [&](int s, Pref& P) {
        int n0 = s * 32;
        const _Float16* kb0 = kbase + (size_t)(n0 + cg) * D + grp * 8;
        const _Float16* kb1 = kbase + (size_t)(n0 + 16 + cg) * D + grp * 8;
        P.bk00 = *(const half8*)(kb0);
        P.bk01 = *(const half8*)(kb0 + 32);
        P.bk10 = *(const half8*)(kb1);
        P.bk11 = *(const half8*)(kb1 + 32);
        P.mb0  = *(const half4v*)(mrow + n0 + grp * 4);
        P.mb1  = *(const half4v*)(mrow + n0 + 16 + grp * 4);
        const _Float16* vb = vbase + n0 + grp * 8;
        P.v0 = *(const half8*)(vb + (size_t)(cg)      * L);
        P.v1 = *(const half8*)(vb + (size_t)(16 + cg) * L);
        P.v2 = *(const half8*)(vb + (size_t)(32 + cg) * L);
        P.v3 = *(const half8*)(vb + (size_t)(48 + cg) * L);
    };

    auto consume = [&](int s, Pref& P) {
        _Float16* tb = slice + (s & 1) * 640;
        {   // tile 0 (keys n0+0..15)
            float4v acc;
            acc[0] = (float)P.mb0[0]; acc[1] = (float)P.mb0[1];
            acc[2] = (float)P.mb0[2]; acc[3] = (float)P.mb0[3];
            acc = __builtin_amdgcn_mfma_f32_16x16x32_f16(P.bk00, aq0, acc, 0, 0, 0);
            acc = __builtin_amdgcn_mfma_f32_16x16x32_f16(P.bk01, aq1, acc, 0, 0, 0);
            float e0 = __expf(acc[0]), e1 = __expf(acc[1]);
            float e2 = __expf(acc[2]), e3 = __expf(acc[3]);
            ls += (e0 + e1) + (e2 + e3);
            half4v ph;
            ph[0] = (_Float16)(e0 * 0.0625f); ph[1] = (_Float16)(e1 * 0.0625f);
            ph[2] = (_Float16)(e2 * 0.0625f); ph[3] = (_Float16)(e3 * 0.0625f);
            *(half4v*)(tb + cg * 40 + grp * 4) = ph;
        }
        {   // tile 1 (keys n0+16..31)
            float4v acc;
            acc[0] = (float)P.mb1[0]; acc[1] = (float)P.mb1[1];
            acc[2] = (float)P.mb1[2]; acc[3] = (float)P.mb1[3];
            acc = __builtin_amdgcn_mfma_f32_16x16x32_f16(P.bk10, aq0, acc, 0, 0, 0);
            acc = __builtin_amdgcn_mfma_f32_16x16x32_f16(P.bk11, aq1, acc, 0, 0, 0);
            float e0 = __expf(acc[0]), e1 = __expf(acc[1]);
            float e2 = __expf(acc[2]), e3 = __expf(acc[3]);
            ls += (e0 + e1) + (e2 + e3);
            half4v ph;
            ph[0] = (_Float16)(e0 * 0.0625f); ph[1] = (_Float16)(e1 * 0.0625f);
            ph[2] = (_Float16)(e2 * 0.0625f); ph[3] = (_Float16)(e3 * 0.0625f);
            *(half4v*)(tb + cg * 40 + 16 + grp * 4) = ph;
        }
        half8 pa = *(const half8*)(tb + cg * 40 + grp * 8);
        oa0 = __builtin_amdgcn_mfma_f32_16x16x32_f16(pa, P.v0, oa0, 0, 0, 0);
        oa1 = __builtin_amdgcn_mfma_f32_16x16x32_f16(pa, P.v1, oa1, 0, 0, 0);
        oa2 = __builtin_amdgcn_mfma_f32_16x16x32_f16(pa, P.v2, oa2, 0, 0, 0);
        oa3 = __builtin_amdgcn_mfma_f32_16x16x32_f16(pa, P.v3, oa3, 0, 0, 0);
    };

    load_step(0, A);
    for (int s = 0; s < 64; s += 2) {
        load_step(s + 1, B);                   // s+1 <= 63 always
        consume(s, A);
        if (s + 2 < 64) load_step(s + 2, A);
        consume(s + 1, B);
    }

    ls += __shfl_xor(ls, 16);
    ls += __shfl_xor(ls, 32);
    float r0 = 16.0f / __shfl(ls, grp * 4 + 0);
    float r1 = 16.0f / __shfl(ls, grp * 4 + 1);
    float r2 = 16.0f / __shfl(ls, grp * 4 + 2);
    float r3 = 16.0f / __shfl(ls, grp * 4 + 3);

    float* ob = out_ho + ((size_t)bh * L + q0) * D;
    ob[(size_t)(grp * 4 + 0) * D +  0 + cg] = oa0[0] * r0;
    ob[(size_t)(grp * 4 + 1) * D +  0 + cg] = oa0[1] * r1;
    ob[(size_t)(grp * 4 + 2) * D +  0 + cg] = oa0[2] * r2;
    ob[(size_t)(grp * 4 + 3) * D +  0 + cg] = oa0[3] * r3;
    ob[(size_t)(grp * 4 + 0) * D + 16 + cg] = oa1[0] * r0;
    ob[(size_t)(grp * 4 + 1) * D + 16 + cg] = oa1[1] * r1;
    ob[(size_t)(grp * 4 + 2) * D + 16 + cg] = oa1[2] * r2;
    ob[(size_t)(grp * 4 + 3) * D + 16 + cg] = oa1[3] * r3;
    ob[(size_t)(grp * 4 + 0) * D + 32 + cg] = oa2[0] * r0;
    ob[(size_t)(grp * 4 + 1) * D + 32 + cg] = oa2[1] * r1;
    ob[(size_t)(grp * 4 + 2) * D + 32 + cg] = oa2[2] * r2;
    ob[(size_t)(grp * 4 + 3) * D + 32 + cg] = oa2[3] * r3;
    ob[(size_t)(grp * 4 + 0) * D + 48 + cg] = oa3[0] * r0;
    ob[(size_t)(grp * 4 + 1) * D + 48 + cg] = oa3[1] * r1;
    ob[(size_t)(grp * 4 + 2) * D + 48 + cg] = oa3[2] * r2;
    ob[(size_t)(grp * 4 + 3) * D + 48 + cg] = oa3[3] * r3;
}

extern "C" void kernel_launch(void* const* d_in, const int* in_sizes, int n_in,
                              void* d_out, int out_size, void* d_ws, size_t ws_size,
                              hipStream_t stream) {
    const float* q    = (const float*)d_in[0];
    const float* k    = (const float*)d_in[1];
    const float* v    = (const float*)d_in[2];
    const int*   mask = (const int*)d_in[3];
    const float* bias = (const float*)d_in[4];

    float* ho   = (float*)d_out;
    float* attn = (float*)d_out + (size_t)NB * NH * L * D;

    char* ws = (char*)d_ws;
    _Float16* qh  = (_Float16*)(ws);                       // 8 MB
    _Float16* kh  = (_Float16*)(ws + ((size_t)8  << 20));  // 8 MB
    _Float16* vt  = (_Float16*)(ws + ((size_t)16 << 20));  // 8 MB
    _Float16* mbh = (_Float16*)(ws + ((size_t)24 << 20));  // 16.8 MB
    (void)in_sizes; (void)n_in; (void)out_size; (void)ws_size;

    prep_qk<<<2048, 256, 0, stream>>>(q, k, qh, kh);
    prep_vt<<<1024, 256, 0, stream>>>(v, vt);
    prep_mbh<<<4096, 256, 0, stream>>>(mask, bias, mbh);
    attn_scores<<<4096, 256, 0, stream>>>(qh, kh, mbh, attn);
    attn_pv<<<1024, 256, 0, stream>>>(qh, kh, vt, mbh, ho);
}

// Round 5
// 532.621 us; speedup vs baseline: 1.2970x; 1.1422x over previous
//
#include <hip/hip_runtime.h>

#define L  2048
#define D  64
#define NH 16
#define NB 2

using half8   = _Float16 __attribute__((ext_vector_type(8)));
using half4v  = _Float16 __attribute__((ext_vector_type(4)));
using float4v = float    __attribute__((ext_vector_type(4)));
using int4v   = int      __attribute__((ext_vector_type(4)));

// ---------------- precompute: qh = fp16(q/8), kh = fp16(k) ----------------
__global__ __launch_bounds__(256) void prep_qk(const float* __restrict__ q,
                                               const float* __restrict__ k,
                                               _Float16* __restrict__ qh,
                                               _Float16* __restrict__ kh) {
    int i = (blockIdx.x * 256 + threadIdx.x) * 8;
    float4v a0 = *(const float4v*)(q + i);
    float4v a1 = *(const float4v*)(q + i + 4);
    float4v b0 = *(const float4v*)(k + i);
    float4v b1 = *(const float4v*)(k + i + 4);
    half8 qo, ko;
#pragma unroll
    for (int j = 0; j < 4; ++j) {
        qo[j]     = (_Float16)(a0[j] * 0.125f);
        qo[4 + j] = (_Float16)(a1[j] * 0.125f);
        ko[j]     = (_Float16)b0[j];
        ko[4 + j] = (_Float16)b1[j];
    }
    *(half8*)(qh + i) = qo;
    *(half8*)(kh + i) = ko;
}

// ---------------- precompute: vt[b,h,d,l] = fp16(v[b,h,l,d]) ----------------
__global__ __launch_bounds__(256) void prep_vt(const float* __restrict__ v,
                                               _Float16* __restrict__ vt) {
    __shared__ float tile[64][65];
    int bh = blockIdx.x >> 5;
    int l0 = (blockIdx.x & 31) * 64;
    const float* vb = v + (size_t)bh * L * D + (size_t)l0 * D;
    int row = threadIdx.x >> 2, c0 = (threadIdx.x & 3) * 16;
#pragma unroll
    for (int j = 0; j < 16; j += 4) {
        float4v t4 = *(const float4v*)(vb + row * D + c0 + j);
        tile[row][c0 + j + 0] = t4[0];
        tile[row][c0 + j + 1] = t4[1];
        tile[row][c0 + j + 2] = t4[2];
        tile[row][c0 + j + 3] = t4[3];
    }
    __syncthreads();
    int d = threadIdx.x >> 2, lq = (threadIdx.x & 3) * 16;
    _Float16* ob = vt + (size_t)bh * D * L + (size_t)d * L + l0 + lq;
    half8 o0, o1;
#pragma unroll
    for (int j = 0; j < 8; ++j) {
        o0[j] = (_Float16)tile[lq + j][d];
        o1[j] = (_Float16)tile[lq + 8 + j][d];
    }
    *(half8*)(ob)     = o0;
    *(half8*)(ob + 8) = o1;
}

// ---------------- precompute: mbh = fp16(mask ? bias : -1000) ----------------
__global__ __launch_bounds__(256) void prep_mbh(const int* __restrict__ mask,
                                                const float* __restrict__ bias,
                                                _Float16* __restrict__ mbh) {
    int i = (blockIdx.x * 256 + threadIdx.x) * 8;
    half8 o;
#pragma unroll
    for (int j = 0; j < 8; j += 4) {
        int4v   m = *(const int4v*)(mask + i + j);
        float4v b = *(const float4v*)(bias + i + j);
        o[j + 0] = (_Float16)(m[0] ? b[0] : -1000.0f);
        o[j + 1] = (_Float16)(m[1] ? b[1] : -1000.0f);
        o[j + 2] = (_Float16)(m[2] ? b[2] : -1000.0f);
        o[j + 3] = (_Float16)(m[3] ? b[3] : -1000.0f);
    }
    *(half8*)(mbh + i) = o;
}

// ---------------- fused attention ----------------
// block = (b, h, 16 q-rows), 4 waves; wave w owns keys [512w, 512w+512).
// Pass 1: l = sum(exp) only (no P storage).  Pass 2: recompute QK (MFMA is
// ~free: 34 GFLOP total), normalize, write attn float4 from regs, PV via
// small per-wave LDS bounce, cross-wave O reduction. Peak VGPR ~122 -> 4
// waves/SIMD, double the previous fused occupancy.
__global__ __launch_bounds__(256, 4) void attn_fused(const _Float16* __restrict__ qh,
                                                     const _Float16* __restrict__ kh,
                                                     const _Float16* __restrict__ vt,
                                                     const _Float16* __restrict__ mbh,
                                                     float* __restrict__ out_ho,
                                                     float* __restrict__ out_attn) {
    __shared__ _Float16 bounce[4][640];        //  5 KB: per-wave 16x32 P tile, 80B rows
    __shared__ float    ored[4][16][68];       // 17 KB: per-wave O partials (pad 68)
    __shared__ float    lpart[4][16];

    int p  = blockIdx.x;                       // XCD x gets l in [512x,512x+512):
    int l  = (p & 7) * 512 + (p >> 3);         // -> (b = x>>2, h2 = x&3): 4 heads/XCD
    int h1 = l & 3, qt = (l >> 2) & 127, h2 = (l >> 9) & 3, b = l >> 11;
    int h  = h2 * 4 + h1;
    int bh = b * NH + h;
    int q0 = qt * 16;

    int tid = threadIdx.x, w = tid >> 6, lane = tid & 63;
    int cg = lane & 15, grp = lane >> 4;

    const _Float16* qbase = qh + ((size_t)bh * L + q0) * D;
    const _Float16* kbase = kh + (size_t)bh * L * D;
    const _Float16* vbase = vt + (size_t)bh * D * L;
    const _Float16* mrow  = mbh + ((size_t)b * L + (q0 + cg)) * L;

    half8 aq0 = *(const half8*)(qbase + cg * D + grp * 8);
    half8 aq1 = *(const half8*)(qbase + cg * D + 32 + grp * 8);

    int k0w = w * 512;

    // ---------------- pass 1: l = sum(exp(s)) ----------------
    float ls = 0.f;
    {
        half8 bkA0, bkA1, bkB0, bkB1;
        half4v mbA, mbB;
        const _Float16* kb = kbase + (size_t)(k0w + cg) * D + grp * 8;
        bkA0 = *(const half8*)(kb);
        bkA1 = *(const half8*)(kb + 32);
        mbA  = *(const half4v*)(mrow + k0w + grp * 4);
#pragma unroll
        for (int f = 0; f < 32; ++f) {
            if (f < 31) {
                int n1 = k0w + (f + 1) * 16;
                const _Float16* kbn = kbase + (size_t)(n1 + cg) * D + grp * 8;
                bkB0 = *(const half8*)(kbn);
                bkB1 = *(const half8*)(kbn + 32);
                mbB  = *(const half4v*)(mrow + n1 + grp * 4);
            }
            float4v acc;
            acc[0] = (float)mbA[0]; acc[1] = (float)mbA[1];
            acc[2] = (float)mbA[2]; acc[3] = (float)mbA[3];
            acc = __builtin_amdgcn_mfma_f32_16x16x32_f16(bkA0, aq0, acc, 0, 0, 0);
            acc = __builtin_amdgcn_mfma_f32_16x16x32_f16(bkA1, aq1, acc, 0, 0, 0);
            ls += (__expf(acc[0]) + __expf(acc[1])) + (__expf(acc[2]) + __expf(acc[3]));
            bkA0 = bkB0; bkA1 = bkB1; mbA = mbB;
        }
    }
    ls += __shfl_xor(ls, 16);
    ls += __shfl_xor(ls, 32);
    if (grp == 0) lpart[w][cg] = ls;
    __syncthreads();
    float rl = 1.0f / (lpart[0][cg] + lpart[1][cg] + lpart[2][cg] + lpart[3][cg]);

    // ---------------- pass 2: recompute, write attn, PV ----------------
    float* abase = out_attn + ((size_t)bh * L + (q0 + cg)) * L;
    _Float16* tb = bounce[w];

    float4v oa0 = {0.f,0.f,0.f,0.f}, oa1 = {0.f,0.f,0.f,0.f};
    float4v oa2 = {0.f,0.f,0.f,0.f}, oa3 = {0.f,0.f,0.f,0.f};

    struct Pref {
        half8 bk00, bk01, bk10, bk11;
        half4v mb0, mb1;
        half8 v0, v1, v2, v3;
    };
    Pref A, B;

    auto load_chunk = [&](int s, Pref& P) {
        int n0 = k0w + s * 32;
        const _Float16* kb0 = kbase + (size_t)(n0 + cg) * D + grp * 8;
        const _Float16* kb1 = kbase + (size_t)(n0 + 16 + cg) * D + grp * 8;
        P.bk00 = *(const half8*)(kb0);
        P.bk01 = *(const half8*)(kb0 + 32);
        P.bk10 = *(const half8*)(kb1);
        P.bk11 = *(const half8*)(kb1 + 32);
        P.mb0  = *(const half4v*)(mrow + n0 + grp * 4);
        P.mb1  = *(const half4v*)(mrow + n0 + 16 + grp * 4);
        const _Float16* vb = vbase + n0 + grp * 8;
        P.v0 = *(const half8*)(vb + (size_t)(cg)      * L);
        P.v1 = *(const half8*)(vb + (size_t)(16 + cg) * L);
        P.v2 = *(const half8*)(vb + (size_t)(32 + cg) * L);
        P.v3 = *(const half8*)(vb + (size_t)(48 + cg) * L);
    };

    auto consume = [&](int s, Pref& P) {
        int n0 = k0w + s * 32;
        {   // keys n0 .. n0+15
            float4v acc;
            acc[0] = (float)P.mb0[0]; acc[1] = (float)P.mb0[1];
            acc[2] = (float)P.mb0[2]; acc[3] = (float)P.mb0[3];
            acc = __builtin_amdgcn_mfma_f32_16x16x32_f16(P.bk00, aq0, acc, 0, 0, 0);
            acc = __builtin_amdgcn_mfma_f32_16x16x32_f16(P.bk01, aq1, acc, 0, 0, 0);
            float4v pn;
            pn[0] = __expf(acc[0]) * rl; pn[1] = __expf(acc[1]) * rl;
            pn[2] = __expf(acc[2]) * rl; pn[3] = __expf(acc[3]) * rl;
            *(float4v*)(abase + n0 + grp * 4) = pn;
            half4v ph;
            ph[0] = (_Float16)pn[0]; ph[1] = (_Float16)pn[1];
            ph[2] = (_Float16)pn[2]; ph[3] = (_Float16)pn[3];
            *(half4v*)(tb + cg * 40 + grp * 4) = ph;
        }
        {   // keys n0+16 .. n0+31
            float4v acc;
            acc[0] = (float)P.mb1[0]; acc[1] = (float)P.mb1[1];
            acc[2] = (float)P.mb1[2]; acc[3] = (float)P.mb1[3];
            acc = __builtin_amdgcn_mfma_f32_16x16x32_f16(P.bk10, aq0, acc, 0, 0, 0);
            acc = __builtin_amdgcn_mfma_f32_16x16x32_f16(P.bk11, aq1, acc, 0, 0, 0);
            float4v pn;
            pn[0] = __expf(acc[0]) * rl; pn[1] = __expf(acc[1]) * rl;
            pn[2] = __expf(acc[2]) * rl; pn[3] = __expf(acc[3]) * rl;
            *(float4v*)(abase + n0 + 16 + grp * 4) = pn;
            half4v ph;
            ph[0] = (_Float16)pn[0]; ph[1] = (_Float16)pn[1];
            ph[2] = (_Float16)pn[2]; ph[3] = (_Float16)pn[3];
            *(half4v*)(tb + cg * 40 + 16 + grp * 4) = ph;
        }
        half8 pa = *(const half8*)(tb + cg * 40 + grp * 8);
        oa0 = __builtin_amdgcn_mfma_f32_16x16x32_f16(pa, P.v0, oa0, 0, 0, 0);
        oa1 = __builtin_amdgcn_mfma_f32_16x16x32_f16(pa, P.v1, oa1, 0, 0, 0);
        oa2 = __builtin_amdgcn_mfma_f32_16x16x32_f16(pa, P.v2, oa2, 0, 0, 0);
        oa3 = __builtin_amdgcn_mfma_f32_16x16x32_f16(pa, P.v3, oa3, 0, 0, 0);
    };

    load_chunk(0, A);
    for (int s = 0; s < 16; s += 2) {
        load_chunk(s + 1, B);
        consume(s, A);
        if (s + 2 < 16) load_chunk(s + 2, A);
        consume(s + 1, B);
    }

    // ---------------- cross-wave O reduction ----------------
    // lane holds O_partial[q = grp*4+r][d = 16*blk + cg] for blk,r in 0..3
    ored[w][grp * 4 + 0][ 0 + cg] = oa0[0];
    ored[w][grp * 4 + 1][ 0 + cg] = oa0[1];
    ored[w][grp * 4 + 2][ 0 + cg] = oa0[2];
    ored[w][grp * 4 + 3][ 0 + cg] = oa0[3];
    ored[w][grp * 4 + 0][16 + cg] = oa1[0];
    ored[w][grp * 4 + 1][16 + cg] = oa1[1];
    ored[w][grp * 4 + 2][16 + cg] = oa1[2];
    ored[w][grp * 4 + 3][16 + cg] = oa1[3];
    ored[w][grp * 4 + 0][32 + cg] = oa2[0];
    ored[w][grp * 4 + 1][32 + cg] = oa2[1];
    ored[w][grp * 4 + 2][32 + cg] = oa2[2];
    ored[w][grp * 4 + 3][32 + cg] = oa2[3];
    ored[w][grp * 4 + 0][48 + cg] = oa3[0];
    ored[w][grp * 4 + 1][48 + cg] = oa3[1];
    ored[w][grp * 4 + 2][48 + cg] = oa3[2];
    ored[w][grp * 4 + 3][48 + cg] = oa3[3];
    __syncthreads();

    // thread t sums 4 partials for (q = t>>4, d = (t&15)*4 .. +3), stores float4
    int qr = tid >> 4, d4 = (tid & 15) * 4;
    float4v o0 = *(const float4v*)&ored[0][qr][d4];
    float4v o1 = *(const float4v*)&ored[1][qr][d4];
    float4v o2 = *(const float4v*)&ored[2][qr][d4];
    float4v o3 = *(const float4v*)&ored[3][qr][d4];
    float4v oo;
    oo[0] = (o0[0] + o1[0]) + (o2[0] + o3[0]);
    oo[1] = (o0[1] + o1[1]) + (o2[1] + o3[1]);
    oo[2] = (o0[2] + o1[2]) + (o2[2] + o3[2]);
    oo[3] = (o0[3] + o1[3]) + (o2[3] + o3[3]);
    *(float4v*)(out_ho + ((size_t)bh * L + q0 + qr) * D + d4) = oo;
}

extern "C" void kernel_launch(void* const* d_in, const int* in_sizes, int n_in,
                              void* d_out, int out_size, void* d_ws, size_t ws_size,
                              hipStream_t stream) {
    const float* q    = (const float*)d_in[0];
    const float* k    = (const float*)d_in[1];
    const float* v    = (const float*)d_in[2];
    const int*   mask = (const int*)d_in[3];
    const float* bias = (const float*)d_in[4];

    float* ho   = (float*)d_out;
    float* attn = (float*)d_out + (size_t)NB * NH * L * D;

    char* ws = (char*)d_ws;
    _Float16* qh  = (_Float16*)(ws);                       // 8 MB
    _Float16* kh  = (_Float16*)(ws + ((size_t)8  << 20));  // 8 MB
    _Float16* vt  = (_Float16*)(ws + ((size_t)16 << 20));  // 8 MB
    _Float16* mbh = (_Float16*)(ws + ((size_t)24 << 20));  // 16.8 MB
    (void)in_sizes; (void)n_in; (void)out_size; (void)ws_size;

    prep_qk<<<2048, 256, 0, stream>>>(q, k, qh, kh);
    prep_vt<<<1024, 256, 0, stream>>>(v, vt);
    prep_mbh<<<4096, 256, 0, stream>>>(mask, bias, mbh);
    attn_fused<<<4096, 256, 0, stream>>>(qh, kh, vt, mbh, ho, attn);
}

// Round 6
// 303.297 us; speedup vs baseline: 2.2777x; 1.7561x over previous
//
#include <hip/hip_runtime.h>

#define L  2048
#define D  64
#define NH 16
#define NB 2
#define KT 32
#define NT 64
#define LOG2E 1.44269504088896f

using half8   = _Float16 __attribute__((ext_vector_type(8)));
using half4v  = _Float16 __attribute__((ext_vector_type(4)));
using float4v = float    __attribute__((ext_vector_type(4)));
using int4v   = int      __attribute__((ext_vector_type(4)));

#define BAR()    asm volatile("s_barrier" ::: "memory")
#define WAITV(n) asm volatile("s_waitcnt vmcnt(" #n ")" ::: "memory")

__device__ __forceinline__ void gload16(const void* g, void* l) {
    __builtin_amdgcn_global_load_lds((const __attribute__((address_space(1))) void*)g,
                                     (__attribute__((address_space(3))) void*)l, 16, 0, 0);
}

// ---------------- precompute: qh = fp16(q * log2e/8), kh = fp16(k) ----------------
__global__ __launch_bounds__(256) void prep_qk(const float* __restrict__ q,
                                               const float* __restrict__ k,
                                               _Float16* __restrict__ qh,
                                               _Float16* __restrict__ kh) {
    int i = (blockIdx.x * 256 + threadIdx.x) * 8;
    float4v a0 = *(const float4v*)(q + i);
    float4v a1 = *(const float4v*)(q + i + 4);
    float4v b0 = *(const float4v*)(k + i);
    float4v b1 = *(const float4v*)(k + i + 4);
    half8 qo, ko;
    const float s = 0.125f * LOG2E;
#pragma unroll
    for (int j = 0; j < 4; ++j) {
        qo[j]     = (_Float16)(a0[j] * s);
        qo[4 + j] = (_Float16)(a1[j] * s);
        ko[j]     = (_Float16)b0[j];
        ko[4 + j] = (_Float16)b1[j];
    }
    *(half8*)(qh + i) = qo;
    *(half8*)(kh + i) = ko;
}

// ---------------- precompute: vt[b,h,d,l] = fp16(v[b,h,l,d]) ----------------
__global__ __launch_bounds__(256) void prep_vt(const float* __restrict__ v,
                                               _Float16* __restrict__ vt) {
    __shared__ float tile[64][65];
    int bh = blockIdx.x >> 5;
    int l0 = (blockIdx.x & 31) * 64;
    const float* vb = v + (size_t)bh * L * D + (size_t)l0 * D;
    int row = threadIdx.x >> 2, c0 = (threadIdx.x & 3) * 16;
#pragma unroll
    for (int j = 0; j < 16; j += 4) {
        float4v t4 = *(const float4v*)(vb + row * D + c0 + j);
        tile[row][c0 + j + 0] = t4[0];
        tile[row][c0 + j + 1] = t4[1];
        tile[row][c0 + j + 2] = t4[2];
        tile[row][c0 + j + 3] = t4[3];
    }
    __syncthreads();
    int d = threadIdx.x >> 2, lq = (threadIdx.x & 3) * 16;
    _Float16* ob = vt + (size_t)bh * D * L + (size_t)d * L + l0 + lq;
    half8 o0, o1;
#pragma unroll
    for (int j = 0; j < 8; ++j) {
        o0[j] = (_Float16)tile[lq + j][d];
        o1[j] = (_Float16)tile[lq + 8 + j][d];
    }
    *(half8*)(ob)     = o0;
    *(half8*)(ob + 8) = o1;
}

// ------- precompute: mbh = fp16(mask ? bias*log2e : -1500) -------
__global__ __launch_bounds__(256) void prep_mbh(const int* __restrict__ mask,
                                                const float* __restrict__ bias,
                                                _Float16* __restrict__ mbh) {
    int i = (blockIdx.x * 256 + threadIdx.x) * 8;
    half8 o;
#pragma unroll
    for (int j = 0; j < 8; j += 4) {
        int4v   m = *(const int4v*)(mask + i + j);
        float4v b = *(const float4v*)(bias + i + j);
        o[j + 0] = (_Float16)(m[0] ? b[0] * LOG2E : -1500.0f);
        o[j + 1] = (_Float16)(m[1] ? b[1] * LOG2E : -1500.0f);
        o[j + 2] = (_Float16)(m[2] ? b[2] * LOG2E : -1500.0f);
        o[j + 3] = (_Float16)(m[3] ? b[3] * LOG2E : -1500.0f);
    }
    *(half8*)(mbh + i) = o;
}

// ---------------- fused attention ----------------
// block = 64 q-rows (wave w owns rows 16w..16w+15) x ALL 2048 keys.
// grid = 1024 = 4 blocks/CU fully resident (LDS 29.5KB, VGPR<=128).
// Keys in KT=32 tiles; K/V/M staged to double-buffered LDS via
// global_load_lds (shared by all 4 waves), raw s_barrier + counted vmcnt.
// Pass1: l = sum(exp2). Pass2: recompute QK, write attn fp32, PV.
// LDS layouts swizzled at the global SOURCE (linear gload_lds dest) so all
// ds_reads are bank-uniform (verified words/bank = floor for each pattern).
__global__ __launch_bounds__(256, 4) void attn_fused(const _Float16* __restrict__ qh,
                                                     const _Float16* __restrict__ kh,
                                                     const _Float16* __restrict__ vt,
                                                     const _Float16* __restrict__ mbh,
                                                     float* __restrict__ out_ho,
                                                     float* __restrict__ out_attn) {
    __shared__ _Float16 kbuf[2][2048];      // [key(32)][d(64)], row XOR-swizzled
    __shared__ _Float16 vbuf[2][2048];      // [kg(4)][d(64)][kl(8)] permuted layout
    __shared__ _Float16 mbuf[2][2048];      // [qrow(64)][key(32)], XOR-swizzled
    __shared__ _Float16 bounce[4][16 * 40]; // per-wave P tile, 80B rows

    int p  = blockIdx.x;                    // XCD x owns 4 consecutive heads of one b
    int l  = (p & 7) * 128 + (p >> 3);
    int b  = l >> 9, h = (l >> 5) & 15, qt = l & 31;
    int bh = b * NH + h;
    int q0b = qt * 64;

    int tid = threadIdx.x, w = tid >> 6, lane = tid & 63;
    int cg = lane & 15, grp = lane >> 4;

    const _Float16* kg = kh  + (size_t)bh * L * D;
    const _Float16* vg = vt  + (size_t)bh * D * L;
    const _Float16* mg = mbh + (size_t)b * L * L;
    const _Float16* qg = qh  + ((size_t)bh * L + q0b + 16 * w) * D;

    half8 aq0 = *(const half8*)(qg + cg * D + grp * 8);
    half8 aq1 = *(const half8*)(qg + cg * D + 32 + grp * 8);

    // staging source offsets (elements); dest = wave base + lane*16B (linear)
    const size_t koff = (size_t)(w * 8 + (lane >> 3)) * D + (((lane & 7) ^ (lane >> 3)) * 8);
    const size_t voff = (size_t)lane * L + w * 8;
    const size_t moff = (size_t)(q0b + w * 16 + (lane >> 2)) * L
                      + ((((lane & 3) * 2) ^ ((lane >> 2) & 6)) * 4);

    auto stage2 = [&](int kt, int bs) {     // pass 1: K + M
        gload16(kg + (size_t)kt * KT * D + koff, &kbuf[bs][w * 512]);
        gload16(mg + (size_t)kt * KT     + moff, &mbuf[bs][w * 512]);
    };
    auto stage3 = [&](int kt, int bs) {     // pass 2: K + M + V
        gload16(kg + (size_t)kt * KT * D + koff, &kbuf[bs][w * 512]);
        gload16(mg + (size_t)kt * KT     + moff, &mbuf[bs][w * 512]);
        gload16(vg + (size_t)kt * KT     + voff, &vbuf[bs][w * 512]);
    };

    // QK for one 16-key subtile; returns exp2(scores) for keys sub*16+grp*4..+3, q=16w+cg
    auto qk_e = [&](const _Float16* kb, const _Float16* mb, int sub) -> float4v {
        int key_loc = sub * 16 + cg;
        half8 bk0 = *(const half8*)(kb + key_loc * 64 + ((grp ^ (cg & 7)) * 8));
        half8 bk1 = *(const half8*)(kb + key_loc * 64 + (((4 + grp) ^ (cg & 7)) * 8));
        half4v m4 = *(const half4v*)(mb + (16 * w + cg) * 32 + (((sub * 4 + grp) ^ (cg & 6)) * 4));
        float4v acc;
        acc[0] = (float)m4[0]; acc[1] = (float)m4[1];
        acc[2] = (float)m4[2]; acc[3] = (float)m4[3];
        acc = __builtin_amdgcn_mfma_f32_16x16x32_f16(bk0, aq0, acc, 0, 0, 0);
        acc = __builtin_amdgcn_mfma_f32_16x16x32_f16(bk1, aq1, acc, 0, 0, 0);
        float4v e;
        e[0] = exp2f(acc[0]); e[1] = exp2f(acc[1]);
        e[2] = exp2f(acc[2]); e[3] = exp2f(acc[3]);
        return e;
    };

    // ---------------- pass 1: row sums ----------------
    float ls = 0.f;
    stage2(0, 0);
    for (int t = 0; t < NT; ++t) {
        int cb = t & 1;
        if (t + 1 < NT) { stage2(t + 1, cb ^ 1); WAITV(2); }
        else            { WAITV(0); }
        BAR();
        float4v e0 = qk_e(kbuf[cb], mbuf[cb], 0);
        float4v e1 = qk_e(kbuf[cb], mbuf[cb], 1);
        ls += ((e0[0] + e0[1]) + (e0[2] + e0[3])) + ((e1[0] + e1[1]) + (e1[2] + e1[3]));
        BAR();
    }
    ls += __shfl_xor(ls, 16);
    ls += __shfl_xor(ls, 32);
    float rl = 1.0f / ls;                  // 1/l for q-row 16w+cg

    // ---------------- pass 2: attn write + PV ----------------
    float* abase = out_attn + ((size_t)bh * L + q0b + 16 * w + cg) * L;
    _Float16* tb = bounce[w];
    float4v oa0 = {0.f,0.f,0.f,0.f}, oa1 = {0.f,0.f,0.f,0.f};
    float4v oa2 = {0.f,0.f,0.f,0.f}, oa3 = {0.f,0.f,0.f,0.f};

    stage3(0, 0);
    for (int t = 0; t < NT; ++t) {
        int cb = t & 1;
        if (t + 1 < NT) {
            stage3(t + 1, cb ^ 1);
            // steady state: [stage(t)x3, stores(t-1)x2, stage(t+1)x3] -> wait
            // until only the newest 5 remain (vmcnt decrements in issue order)
            // => stage(t) done, attn stores NOT drained. t=0 has no stores.
            if (t == 0) { WAITV(3); } else { WAITV(5); }
        } else { WAITV(0); }
        BAR();
#pragma unroll
        for (int sub = 0; sub < 2; ++sub) {
            float4v e = qk_e(kbuf[cb], mbuf[cb], sub);
            float4v pn;
            pn[0] = e[0] * rl; pn[1] = e[1] * rl;
            pn[2] = e[2] * rl; pn[3] = e[3] * rl;
            *(float4v*)(abase + t * KT + sub * 16 + grp * 4) = pn;
            half4v ph;
            ph[0] = (_Float16)pn[0]; ph[1] = (_Float16)pn[1];
            ph[2] = (_Float16)pn[2]; ph[3] = (_Float16)pn[3];
            *(half4v*)(tb + cg * 40 + sub * 16 + grp * 4) = ph;
        }
        half8 pa = *(const half8*)(tb + cg * 40 + grp * 8);
        const _Float16* vb = vbuf[cb];
        half8 pv0 = *(const half8*)(vb + (grp * 64 +  0 + cg) * 8);
        half8 pv1 = *(const half8*)(vb + (grp * 64 + 16 + cg) * 8);
        half8 pv2 = *(const half8*)(vb + (grp * 64 + 32 + cg) * 8);
        half8 pv3 = *(const half8*)(vb + (grp * 64 + 48 + cg) * 8);
        oa0 = __builtin_amdgcn_mfma_f32_16x16x32_f16(pa, pv0, oa0, 0, 0, 0);
        oa1 = __builtin_amdgcn_mfma_f32_16x16x32_f16(pa, pv1, oa1, 0, 0, 0);
        oa2 = __builtin_amdgcn_mfma_f32_16x16x32_f16(pa, pv2, oa2, 0, 0, 0);
        oa3 = __builtin_amdgcn_mfma_f32_16x16x32_f16(pa, pv3, oa3, 0, 0, 0);
        BAR();
    }

    // O[q = grp*4+r][d = 16*blk + cg], already normalized (P was normalized)
    float* ob = out_ho + ((size_t)bh * L + q0b + 16 * w) * D;
    ob[(size_t)(grp * 4 + 0) * D +  0 + cg] = oa0[0];
    ob[(size_t)(grp * 4 + 1) * D +  0 + cg] = oa0[1];
    ob[(size_t)(grp * 4 + 2) * D +  0 + cg] = oa0[2];
    ob[(size_t)(grp * 4 + 3) * D +  0 + cg] = oa0[3];
    ob[(size_t)(grp * 4 + 0) * D + 16 + cg] = oa1[0];
    ob[(size_t)(grp * 4 + 1) * D + 16 + cg] = oa1[1];
    ob[(size_t)(grp * 4 + 2) * D + 16 + cg] = oa1[2];
    ob[(size_t)(grp * 4 + 3) * D + 16 + cg] = oa1[3];
    ob[(size_t)(grp * 4 + 0) * D + 32 + cg] = oa2[0];
    ob[(size_t)(grp * 4 + 1) * D + 32 + cg] = oa2[1];
    ob[(size_t)(grp * 4 + 2) * D + 32 + cg] = oa2[2];
    ob[(size_t)(grp * 4 + 3) * D + 32 + cg] = oa2[3];
    ob[(size_t)(grp * 4 + 0) * D + 48 + cg] = oa3[0];
    ob[(size_t)(grp * 4 + 1) * D + 48 + cg] = oa3[1];
    ob[(size_t)(grp * 4 + 2) * D + 48 + cg] = oa3[2];
    ob[(size_t)(grp * 4 + 3) * D + 48 + cg] = oa3[3];
}

extern "C" void kernel_launch(void* const* d_in, const int* in_sizes, int n_in,
                              void* d_out, int out_size, void* d_ws, size_t ws_size,
                              hipStream_t stream) {
    const float* q    = (const float*)d_in[0];
    const float* k    = (const float*)d_in[1];
    const float* v    = (const float*)d_in[2];
    const int*   mask = (const int*)d_in[3];
    const float* bias = (const float*)d_in[4];

    float* ho   = (float*)d_out;
    float* attn = (float*)d_out + (size_t)NB * NH * L * D;

    char* ws = (char*)d_ws;
    _Float16* qh  = (_Float16*)(ws);                       // 8 MB
    _Float16* kh  = (_Float16*)(ws + ((size_t)8  << 20));  // 8 MB
    _Float16* vt  = (_Float16*)(ws + ((size_t)16 << 20));  // 8 MB
    _Float16* mbh = (_Float16*)(ws + ((size_t)24 << 20));  // 16.8 MB
    (void)in_sizes; (void)n_in; (void)out_size; (void)ws_size;

    prep_qk<<<2048, 256, 0, stream>>>(q, k, qh, kh);
    prep_vt<<<1024, 256, 0, stream>>>(v, vt);
    prep_mbh<<<4096, 256, 0, stream>>>(mask, bias, mbh);
    attn_fused<<<1024, 256, 0, stream>>>(qh, kh, vt, mbh, ho, attn);
}

// Round 7
// 251.609 us; speedup vs baseline: 2.7456x; 1.2054x over previous
//
#include <hip/hip_runtime.h>

#define L  2048
#define D  64
#define NH 16
#define NB 2
#define KT 32
#define NT 64
#define LOG2E 1.44269504088896f

using half8   = _Float16 __attribute__((ext_vector_type(8)));
using half4v  = _Float16 __attribute__((ext_vector_type(4)));
using float4v = float    __attribute__((ext_vector_type(4)));
using int4v   = int      __attribute__((ext_vector_type(4)));

#define BAR()    asm volatile("s_barrier" ::: "memory")
#define WAITV(n) asm volatile("s_waitcnt vmcnt(" #n ")" ::: "memory")

__device__ __forceinline__ void gload16(const void* g, void* l) {
    __builtin_amdgcn_global_load_lds((const __attribute__((address_space(1))) void*)g,
                                     (__attribute__((address_space(3))) void*)l, 16, 0, 0);
}

// ---------------- precompute: qh = fp16(q * log2e/8), kh = fp16(k) ----------------
__global__ __launch_bounds__(256) void prep_qk(const float* __restrict__ q,
                                               const float* __restrict__ k,
                                               _Float16* __restrict__ qh,
                                               _Float16* __restrict__ kh) {
    int i = (blockIdx.x * 256 + threadIdx.x) * 8;
    float4v a0 = *(const float4v*)(q + i);
    float4v a1 = *(const float4v*)(q + i + 4);
    float4v b0 = *(const float4v*)(k + i);
    float4v b1 = *(const float4v*)(k + i + 4);
    half8 qo, ko;
    const float s = 0.125f * LOG2E;
#pragma unroll
    for (int j = 0; j < 4; ++j) {
        qo[j]     = (_Float16)(a0[j] * s);
        qo[4 + j] = (_Float16)(a1[j] * s);
        ko[j]     = (_Float16)b0[j];
        ko[4 + j] = (_Float16)b1[j];
    }
    *(half8*)(qh + i) = qo;
    *(half8*)(kh + i) = ko;
}

// ---------------- precompute: vt[b,h,d,l] = fp16(v[b,h,l,d]) ----------------
__global__ __launch_bounds__(256) void prep_vt(const float* __restrict__ v,
                                               _Float16* __restrict__ vt) {
    __shared__ float tile[64][65];
    int bh = blockIdx.x >> 5;
    int l0 = (blockIdx.x & 31) * 64;
    const float* vb = v + (size_t)bh * L * D + (size_t)l0 * D;
    int row = threadIdx.x >> 2, c0 = (threadIdx.x & 3) * 16;
#pragma unroll
    for (int j = 0; j < 16; j += 4) {
        float4v t4 = *(const float4v*)(vb + row * D + c0 + j);
        tile[row][c0 + j + 0] = t4[0];
        tile[row][c0 + j + 1] = t4[1];
        tile[row][c0 + j + 2] = t4[2];
        tile[row][c0 + j + 3] = t4[3];
    }
    __syncthreads();
    int d = threadIdx.x >> 2, lq = (threadIdx.x & 3) * 16;
    _Float16* ob = vt + (size_t)bh * D * L + (size_t)d * L + l0 + lq;
    half8 o0, o1;
#pragma unroll
    for (int j = 0; j < 8; ++j) {
        o0[j] = (_Float16)tile[lq + j][d];
        o1[j] = (_Float16)tile[lq + 8 + j][d];
    }
    *(half8*)(ob)     = o0;
    *(half8*)(ob + 8) = o1;
}

// ------- precompute: mbh = fp16(mask ? bias*log2e : -1500) -------
__global__ __launch_bounds__(256) void prep_mbh(const int* __restrict__ mask,
                                                const float* __restrict__ bias,
                                                _Float16* __restrict__ mbh) {
    int i = (blockIdx.x * 256 + threadIdx.x) * 8;
    half8 o;
#pragma unroll
    for (int j = 0; j < 8; j += 4) {
        int4v   m = *(const int4v*)(mask + i + j);
        float4v b = *(const float4v*)(bias + i + j);
        o[j + 0] = (_Float16)(m[0] ? b[0] * LOG2E : -1500.0f);
        o[j + 1] = (_Float16)(m[1] ? b[1] * LOG2E : -1500.0f);
        o[j + 2] = (_Float16)(m[2] ? b[2] * LOG2E : -1500.0f);
        o[j + 3] = (_Float16)(m[3] ? b[3] * LOG2E : -1500.0f);
    }
    *(half8*)(mbh + i) = o;
}

// ---------------- fused attention ----------------
// Identical structure to R6 (KT=32 double-buffered gload_lds staging, raw
// s_barrier + counted vmcnt, pass1 = row sums, pass2 = recompute + attn + PV)
// EXCEPT the store path: normalized P bounces through a per-wave fp32 LDS
// tile (stride 33: 2-way-free b128 reads) and is stored NONTEMPORALLY as
// 8-row x 128B-contiguous dwordx4 -> no L2 write-allocate pollution, better
// DRAM page locality. setprio(1) wraps MFMA clusters (T5).
__global__ __launch_bounds__(256, 4) void attn_fused(const _Float16* __restrict__ qh,
                                                     const _Float16* __restrict__ kh,
                                                     const _Float16* __restrict__ vt,
                                                     const _Float16* __restrict__ mbh,
                                                     float* __restrict__ out_ho,
                                                     float* __restrict__ out_attn) {
    __shared__ _Float16 kbuf[2][2048];      // [key(32)][d(64)], row XOR-swizzled
    __shared__ _Float16 vbuf[2][2048];      // [kg(4)][d(64)][kl(8)] permuted layout
    __shared__ _Float16 mbuf[2][2048];      // [qrow(64)][key(32)], XOR-swizzled
    __shared__ _Float16 bounce[4][640];     // per-wave P fp16 (PV A-frag), 80B rows
    __shared__ float    bounce32[4][528];   // per-wave P fp32 (store path), stride 33

    int p  = blockIdx.x;                    // XCD x owns 4 consecutive heads of one b
    int l  = (p & 7) * 128 + (p >> 3);
    int b  = l >> 9, h = (l >> 5) & 15, qt = l & 31;
    int bh = b * NH + h;
    int q0b = qt * 64;

    int tid = threadIdx.x, w = tid >> 6, lane = tid & 63;
    int cg = lane & 15, grp = lane >> 4;

    const _Float16* kg = kh  + (size_t)bh * L * D;
    const _Float16* vg = vt  + (size_t)bh * D * L;
    const _Float16* mg = mbh + (size_t)b * L * L;
    const _Float16* qg = qh  + ((size_t)bh * L + q0b + 16 * w) * D;

    half8 aq0 = *(const half8*)(qg + cg * D + grp * 8);
    half8 aq1 = *(const half8*)(qg + cg * D + 32 + grp * 8);

    // staging source offsets (elements); dest = wave base + lane*16B (linear)
    const size_t koff = (size_t)(w * 8 + (lane >> 3)) * D + (((lane & 7) ^ (lane >> 3)) * 8);
    const size_t voff = (size_t)lane * L + w * 8;
    const size_t moff = (size_t)(q0b + w * 16 + (lane >> 2)) * L
                      + ((((lane & 3) * 2) ^ ((lane >> 2) & 6)) * 4);

    auto stage2 = [&](int kt, int bs) {     // pass 1: K + M
        gload16(kg + (size_t)kt * KT * D + koff, &kbuf[bs][w * 512]);
        gload16(mg + (size_t)kt * KT     + moff, &mbuf[bs][w * 512]);
    };
    auto stage3 = [&](int kt, int bs) {     // pass 2: K + M + V
        gload16(kg + (size_t)kt * KT * D + koff, &kbuf[bs][w * 512]);
        gload16(mg + (size_t)kt * KT     + moff, &mbuf[bs][w * 512]);
        gload16(vg + (size_t)kt * KT     + voff, &vbuf[bs][w * 512]);
    };

    // QK for one 16-key subtile -> exp2(scores), keys sub*16+grp*4..+3, q=16w+cg
    auto qk_e = [&](const _Float16* kb, const _Float16* mb, int sub) -> float4v {
        int key_loc = sub * 16 + cg;
        half8 bk0 = *(const half8*)(kb + key_loc * 64 + ((grp ^ (cg & 7)) * 8));
        half8 bk1 = *(const half8*)(kb + key_loc * 64 + (((4 + grp) ^ (cg & 7)) * 8));
        half4v m4 = *(const half4v*)(mb + (16 * w + cg) * 32 + (((sub * 4 + grp) ^ (cg & 6)) * 4));
        float4v acc;
        acc[0] = (float)m4[0]; acc[1] = (float)m4[1];
        acc[2] = (float)m4[2]; acc[3] = (float)m4[3];
        acc = __builtin_amdgcn_mfma_f32_16x16x32_f16(bk0, aq0, acc, 0, 0, 0);
        acc = __builtin_amdgcn_mfma_f32_16x16x32_f16(bk1, aq1, acc, 0, 0, 0);
        float4v e;
        e[0] = exp2f(acc[0]); e[1] = exp2f(acc[1]);
        e[2] = exp2f(acc[2]); e[3] = exp2f(acc[3]);
        return e;
    };

    // ---------------- pass 1: row sums ----------------
    float ls = 0.f;
    stage2(0, 0);
    for (int t = 0; t < NT; ++t) {
        int cb = t & 1;
        if (t + 1 < NT) { stage2(t + 1, cb ^ 1); WAITV(2); }
        else            { WAITV(0); }
        BAR();
        __builtin_amdgcn_s_setprio(1);
        float4v e0 = qk_e(kbuf[cb], mbuf[cb], 0);
        float4v e1 = qk_e(kbuf[cb], mbuf[cb], 1);
        __builtin_amdgcn_s_setprio(0);
        ls += ((e0[0] + e0[1]) + (e0[2] + e0[3])) + ((e1[0] + e1[1]) + (e1[2] + e1[3]));
        BAR();
    }
    ls += __shfl_xor(ls, 16);
    ls += __shfl_xor(ls, 32);
    float rl = 1.0f / ls;                  // 1/l for q-row 16w+cg

    // ---------------- pass 2: attn write + PV ----------------
    _Float16* tb  = bounce[w];
    float*    t32 = bounce32[w];
    float* arow = out_attn + ((size_t)bh * L + q0b + 16 * w) * L;   // wave's 16 rows
    float4v oa0 = {0.f,0.f,0.f,0.f}, oa1 = {0.f,0.f,0.f,0.f};
    float4v oa2 = {0.f,0.f,0.f,0.f}, oa3 = {0.f,0.f,0.f,0.f};
    int sr = lane >> 3, sc = (lane & 7) * 4;   // store-sweep coords

    stage3(0, 0);
    for (int t = 0; t < NT; ++t) {
        int cb = t & 1;
        if (t + 1 < NT) {
            stage3(t + 1, cb ^ 1);
            // steady state outstanding: stage(t)3 + stores(t-1)2 + stage(t+1)3
            // -> wait newest 5 (stage(t) done, stores NOT drained). t=0: no stores.
            if (t == 0) { WAITV(3); } else { WAITV(5); }
        } else { WAITV(0); }
        BAR();
        __builtin_amdgcn_s_setprio(1);
#pragma unroll
        for (int sub = 0; sub < 2; ++sub) {
            float4v e = qk_e(kbuf[cb], mbuf[cb], sub);
            float4v pn;
            pn[0] = e[0] * rl; pn[1] = e[1] * rl;
            pn[2] = e[2] * rl; pn[3] = e[3] * rl;
            *(float4v*)&t32[cg * 33 + sub * 16 + grp * 4] = pn;   // fp32 store path
            half4v ph;
            ph[0] = (_Float16)pn[0]; ph[1] = (_Float16)pn[1];
            ph[2] = (_Float16)pn[2]; ph[3] = (_Float16)pn[3];
            *(half4v*)(tb + cg * 40 + sub * 16 + grp * 4) = ph;   // fp16 PV path
        }
        __builtin_amdgcn_s_setprio(0);
        // nontemporal attn stores: 2 instrs, each 8 rows x 128B contiguous
        {
            float4v s0 = *(const float4v*)&t32[(sr)     * 33 + sc];
            float4v s1 = *(const float4v*)&t32[(sr + 8) * 33 + sc];
            __builtin_nontemporal_store(s0, (float4v*)(arow + (size_t)(sr)     * L + t * KT + sc));
            __builtin_nontemporal_store(s1, (float4v*)(arow + (size_t)(sr + 8) * L + t * KT + sc));
        }
        half8 pa = *(const half8*)(tb + cg * 40 + grp * 8);
        const _Float16* vb = vbuf[cb];
        half8 pv0 = *(const half8*)(vb + (grp * 64 +  0 + cg) * 8);
        half8 pv1 = *(const half8*)(vb + (grp * 64 + 16 + cg) * 8);
        half8 pv2 = *(const half8*)(vb + (grp * 64 + 32 + cg) * 8);
        half8 pv3 = *(const half8*)(vb + (grp * 64 + 48 + cg) * 8);
        __builtin_amdgcn_s_setprio(1);
        oa0 = __builtin_amdgcn_mfma_f32_16x16x32_f16(pa, pv0, oa0, 0, 0, 0);
        oa1 = __builtin_amdgcn_mfma_f32_16x16x32_f16(pa, pv1, oa1, 0, 0, 0);
        oa2 = __builtin_amdgcn_mfma_f32_16x16x32_f16(pa, pv2, oa2, 0, 0, 0);
        oa3 = __builtin_amdgcn_mfma_f32_16x16x32_f16(pa, pv3, oa3, 0, 0, 0);
        __builtin_amdgcn_s_setprio(0);
        BAR();
    }

    // O[q = grp*4+r][d = 16*blk + cg], already normalized (P was normalized)
    float* ob = out_ho + ((size_t)bh * L + q0b + 16 * w) * D;
#pragma unroll
    for (int r = 0; r < 4; ++r) {
        size_t ro = (size_t)(grp * 4 + r) * D;
        __builtin_nontemporal_store(oa0[r], ob + ro +  0 + cg);
        __builtin_nontemporal_store(oa1[r], ob + ro + 16 + cg);
        __builtin_nontemporal_store(oa2[r], ob + ro + 32 + cg);
        __builtin_nontemporal_store(oa3[r], ob + ro + 48 + cg);
    }
}

extern "C" void kernel_launch(void* const* d_in, const int* in_sizes, int n_in,
                              void* d_out, int out_size, void* d_ws, size_t ws_size,
                              hipStream_t stream) {
    const float* q    = (const float*)d_in[0];
    const float* k    = (const float*)d_in[1];
    const float* v    = (const float*)d_in[2];
    const int*   mask = (const int*)d_in[3];
    const float* bias = (const float*)d_in[4];

    float* ho   = (float*)d_out;
    float* attn = (float*)d_out + (size_t)NB * NH * L * D;

    char* ws = (char*)d_ws;
    _Float16* qh  = (_Float16*)(ws);                       // 8 MB
    _Float16* kh  = (_Float16*)(ws + ((size_t)8  << 20));  // 8 MB
    _Float16* vt  = (_Float16*)(ws + ((size_t)16 << 20));  // 8 MB
    _Float16* mbh = (_Float16*)(ws + ((size_t)24 << 20));  // 16.8 MB
    (void)in_sizes; (void)n_in; (void)out_size; (void)ws_size;

    prep_qk<<<2048, 256, 0, stream>>>(q, k, qh, kh);
    prep_vt<<<1024, 256, 0, stream>>>(v, vt);
    prep_mbh<<<4096, 256, 0, stream>>>(mask, bias, mbh);
    attn_fused<<<1024, 256, 0, stream>>>(qh, kh, vt, mbh, ho, attn);
}